// Round 5
// baseline (101.037 us; speedup 1.0000x reference)
//
#include <hip/hip_runtime.h>
#include <float.h>
#include <math.h>

#define BATCH 4
#define NPTS 4096
#define BLK 256
#define QCH 8                      // queries/thread, chamfer (4 f32x2 pairs)
#define QR 4                       // queries/thread, repulsion (2 f32x2 pairs)
#define SEG_CH 64                  // chamfer segments (64 pts each)
#define TPTS_CH 64
#define SEG_R 32                   // repulsion segments (128 pts each)
#define TPTS_R 128
#define H2 (0.03f * 0.03f)
#define RADIUS_C 0.07f
#define EPS_C 1e-12f
#define T2 0.05f                   // rep d^2 cutoff: excluded contribs ~1e-25
#define NQ (BATCH * NPTS)          // 16384
#define NCH (2 * NQ)               // 32768 chamfer (type,b,q) rows

// d_ws (16 MB + 4 KB):
//   minseg  : float [SEG_CH][NCH]   (8 MB)   @ 0
//   top4    : float4[SEG_R][NQ]     (8 MB)   @ 8 MB
//   chamsum : float [512]                    @ 16 MB
//   repsum  : float [512]                    @ 16 MB + 2048
//
// R12: dur = fill(~46.5 fixed) + partial(~24) + merge(~7) + finalize/gaps(~5).
// Partial is VALU+LDS co-bound (~10us each pipe, ~50% eff). Levers:
//  (a) v_pk_fma_f32 via __builtin_elementwise_fma on query-PAIRS (f32x2):
//      coeffs stay 3 regs/query, targets splat; bit-exact same fma nesting;
//      q2 recomputed as 0.25*(nx^2+ny^2+nz^2) = exact pow2 rescale of the
//      reference rounding chain. Fallback = scalar fma (no regression).
//  (b) rep TPTS 128 (SEG_R=32): top4 16->8 MB, rep blocks (1024q x 128t)
//      duration-uniform with chamfer (2048q x 64t) -> 1536 blocks [C,C,R],
//      6/CU, 24 waves/CU, one uniform round. Merge keeps R11's no-atomic
//      per-block-sum + 1-block finalize (the R10 regression fix).

typedef float f32x2 __attribute__((ext_vector_type(2)));
#define PKFMA(a, b, c) __builtin_elementwise_fma((a), (b), (c))

template <bool EXCL>
__device__ __forceinline__ void rep_loop(
    const float4* __restrict__ s, int base, const int (&q)[QR],
    const f32x2 (&pnx)[2], const f32x2 (&pny)[2], const f32x2 (&pnz)[2],
    float (&m)[QR][4])
{
    #pragma unroll 2
    for (int j = 0; j < TPTS_R; ++j) {
        float4 t = s[j];
        f32x2 tx = {t.x, t.x}, ty = {t.y, t.y}, tz = {t.z, t.z}, tw = {t.w, t.w};
        f32x2 h0 = PKFMA(pnx[0], tx, PKFMA(pny[0], ty, PKFMA(pnz[0], tz, tw)));
        f32x2 h1 = PKFMA(pnx[1], tx, PKFMA(pny[1], ty, PKFMA(pnz[1], tz, tw)));
        float hv[QR] = {h0.x, h0.y, h1.x, h1.y};
        if (EXCL) {
            #pragma unroll
            for (int r = 0; r < QR; ++r)
                hv[r] = (base + j == q[r]) ? FLT_MAX : hv[r];  // exclude self
        }
        #pragma unroll
        for (int p = 0; p < 2; ++p) {                          // per-pair gate
            if (__any((hv[2 * p] < m[2 * p][3]) | (hv[2 * p + 1] < m[2 * p + 1][3]))) {
                #pragma unroll
                for (int r = 2 * p; r < 2 * p + 2; ++r) {      // insert (idempotent)
                    float hvv = hv[r];
                    float n0 = fminf(m[r][0], hvv); float u0 = fmaxf(m[r][0], hvv);
                    float n1 = fminf(m[r][1], u0);  float u1 = fmaxf(m[r][1], u0);
                    float n2 = fminf(m[r][2], u1);  float u2 = fmaxf(m[r][2], u1);
                    float n3 = fminf(m[r][3], u2);
                    m[r][0] = n0; m[r][1] = n1; m[r][2] = n2; m[r][3] = n3;
                }
            }
        }
    }
}

// 1536 blocks, pattern [C,C,R]: chamfer cid = (g/3)*2 + g%3 in [0,1024),
// rep rid = g/3 in [0,512). Every block = 131072 pair-evals (uniform, no tail).
__global__ __launch_bounds__(BLK) void partial_kernel(
    const float* __restrict__ pred, const float* __restrict__ gt,
    float* __restrict__ minseg, float4* __restrict__ top4)
{
    __shared__ float4 s[TPTS_R];   // up to 128 x (x,y,z,|t|^2) = 2 KB

    const int g   = blockIdx.x;
    const int r3  = g % 3;
    const int id  = g / 3;
    const bool isrep = (r3 == 2);

    int type, b, qblk, seg;
    if (!isrep) {
        int cid = id * 2 + r3;     // [0,1024)
        qblk = cid & 1; type = (cid >> 1) & 1; b = (cid >> 2) & 3; seg = cid >> 4; // <64
    } else {
        qblk = id & 3; type = 2;   b = (id >> 2) & 3; seg = id >> 4;               // <32
    }
    const float* qbase = (type == 1) ? gt : pred;
    const float* tbase = (type == 0) ? gt : pred;
    const int npts = isrep ? TPTS_R : TPTS_CH;

    // stage npts targets: threads 0..npts/2-1, 2 points each, |t|^2 on the fly
    if (threadIdx.x < (npts >> 1)) {
        const float2* g2 = (const float2*)(tbase + ((size_t)b * NPTS + seg * npts) * 3);
        float2 a = g2[3 * threadIdx.x + 0];
        float2 c = g2[3 * threadIdx.x + 1];
        float2 e = g2[3 * threadIdx.x + 2];
        float t20 = fmaf(a.x, a.x, fmaf(a.y, a.y, c.x * c.x));
        float t21 = fmaf(c.y, c.y, fmaf(e.x, e.x, e.y * e.y));
        s[2 * threadIdx.x + 0] = make_float4(a.x, a.y, c.x, t20);
        s[2 * threadIdx.x + 1] = make_float4(c.y, e.x, e.y, t21);
    }
    __syncthreads();

    if (!isrep) {
        const int q0 = qblk * (BLK * QCH) + threadIdx.x;      // qblk*2048 + tid
        f32x2 cnx[4], cny[4], cnz[4], cmn[4];
        #pragma unroll
        for (int p = 0; p < 4; ++p) {
            const float* qa = qbase + ((size_t)b * NPTS + q0 + (2 * p) * BLK) * 3;
            const float* qb2 = qbase + ((size_t)b * NPTS + q0 + (2 * p + 1) * BLK) * 3;
            cnx[p] = f32x2{-2.f * qa[0], -2.f * qb2[0]};
            cny[p] = f32x2{-2.f * qa[1], -2.f * qb2[1]};
            cnz[p] = f32x2{-2.f * qa[2], -2.f * qb2[2]};
            cmn[p] = f32x2{FLT_MAX, FLT_MAX};
        }
        #pragma unroll 2
        for (int j = 0; j < TPTS_CH; j += 2) {
            float4 t0 = s[j], t1 = s[j + 1];
            f32x2 t0x = {t0.x, t0.x}, t0y = {t0.y, t0.y}, t0z = {t0.z, t0.z}, t0w = {t0.w, t0.w};
            f32x2 t1x = {t1.x, t1.x}, t1y = {t1.y, t1.y}, t1z = {t1.z, t1.z}, t1w = {t1.w, t1.w};
            #pragma unroll
            for (int p = 0; p < 4; ++p) {
                f32x2 h0 = PKFMA(cnx[p], t0x, PKFMA(cny[p], t0y, PKFMA(cnz[p], t0z, t0w)));
                f32x2 h1 = PKFMA(cnx[p], t1x, PKFMA(cny[p], t1y, PKFMA(cnz[p], t1z, t1w)));
                cmn[p].x = fminf(fminf(cmn[p].x, h0.x), h1.x);   // -> v_min3_f32
                cmn[p].y = fminf(fminf(cmn[p].y, h0.y), h1.y);
            }
        }
        float* row = minseg + (size_t)seg * NCH + (type * BATCH + b) * NPTS;
        #pragma unroll
        for (int p = 0; p < 4; ++p) {
            // q2 = 0.25*(nz^2 +fma ny^2 +fma nx^2): exact 4x-scaled replica of
            // fmaf(qx,qx,fmaf(qy,qy,qz*qz)) rounding chain.
            f32x2 tq = PKFMA(cnx[p], cnx[p], PKFMA(cny[p], cny[p], cnz[p] * cnz[p]));
            row[q0 + (2 * p) * BLK]     = cmn[p].x + 0.25f * tq.x;
            row[q0 + (2 * p + 1) * BLK] = cmn[p].y + 0.25f * tq.y;
        }
    } else {
        const int qb = qblk * (BLK * QR) + threadIdx.x;       // qblk*1024 + tid
        int   q[QR];
        f32x2 pnx[2], pny[2], pnz[2];
        float q2[QR];
        float m[QR][4];
        #pragma unroll
        for (int p = 0; p < 2; ++p) {
            float qx[2], qy[2], qz[2];
            #pragma unroll
            for (int h = 0; h < 2; ++h) {
                int r = 2 * p + h;
                q[r] = qb + r * BLK;
                const float* qa = qbase + ((size_t)b * NPTS + q[r]) * 3;
                qx[h] = qa[0]; qy[h] = qa[1]; qz[h] = qa[2];
                q2[r] = fmaf(qx[h], qx[h], fmaf(qy[h], qy[h], qz[h] * qz[h]));
                // h-space cutoff init: h < T2 - q2  <=>  d2 < T2
                float a = T2 - q2[r];
                m[r][0] = a; m[r][1] = a; m[r][2] = a; m[r][3] = a;
            }
            pnx[p] = f32x2{-2.f * qx[0], -2.f * qx[1]};
            pny[p] = f32x2{-2.f * qy[0], -2.f * qy[1]};
            pnz[p] = f32x2{-2.f * qz[0], -2.f * qz[1]};
        }
        const int base = seg * TPTS_R;
        // queries [qblk*1024, +1024) overlap targets [seg*128, +128) iff seg>>3==qblk
        if ((seg >> 3) == qblk)
            rep_loop<true >(s, base, q, pnx, pny, pnz, m);
        else
            rep_loop<false>(s, base, q, pnx, pny, pnz, m);

        float4* dst = top4 + (size_t)seg * NQ + b * NPTS;
        #pragma unroll
        for (int r = 0; r < QR; ++r)
            dst[q[r]] = make_float4(m[r][0] + q2[r], m[r][1] + q2[r],
                                    m[r][2] + q2[r], m[r][3] + q2[r]);
    }
}

// 1024 blocks: even = chamfer merge (512 x 64 queries, 4 grp x 16 segs),
// odd = rep merge (512 x 32 queries, 8 grp x 4 segs). Seg-split across
// thread groups + LDS tree -> 1 latency round. NO atomics/fences: each
// block writes one float to chamsum[c]/repsum[c].
__global__ __launch_bounds__(BLK) void merge_kernel(
    const float* __restrict__ minseg, const float4* __restrict__ top4,
    float* __restrict__ chamsum, float* __restrict__ repsum)
{
    __shared__ float4 l4[8][32];                   // rep lists; aliased for chamfer
    float* red = (float*)l4;                       // [4][64] floats for chamfer

    float contrib = 0.f;
    const int c = blockIdx.x >> 1;                 // [0,512)
    if (!(blockIdx.x & 1)) {
        // ---- chamfer: 64 queries, 4 groups x 16 segs ----
        const int q   = c * 64 + (threadIdx.x & 63);
        const int grp = threadIdx.x >> 6;          // 0..3
        float m = FLT_MAX;
        #pragma unroll                             // 16 independent loads in flight
        for (int u = 0; u < 16; ++u)
            m = fminf(m, minseg[(size_t)(grp * 16 + u) * NCH + q]);
        red[grp * 64 + (threadIdx.x & 63)] = m;
        __syncthreads();
        if (threadIdx.x < 64) {
            float mm = fminf(fminf(red[threadIdx.x],       red[64  + threadIdx.x]),
                             fminf(red[128 + threadIdx.x], red[192 + threadIdx.x]));
            contrib = fmaxf(mm, 0.f);              // clamp as in reference
            #pragma unroll
            for (int off = 32; off > 0; off >>= 1)
                contrib += __shfl_down(contrib, off, 64);
            if (threadIdx.x == 0) chamsum[c] = contrib;
        }
    } else {
        // ---- repulsion: 32 queries, 8 groups x 4 segs ----
        const int q   = c * 32 + (threadIdx.x & 31);
        const int grp = threadIdx.x >> 5;          // 0..7
        float m0 = FLT_MAX, m1 = FLT_MAX, m2 = FLT_MAX, m3 = FLT_MAX;
        #pragma unroll                             // 4 float4 loads in flight
        for (int u = 0; u < 4; ++u) {
            float4 v = top4[(size_t)(grp * 4 + u) * NQ + q];
            const float vals[4] = {v.x, v.y, v.z, v.w};
            #pragma unroll
            for (int k = 0; k < 4; ++k) {
                float h = vals[k];
                if (h < m3) {                      // mostly T2 sentinel -> skip
                    float n0 = fminf(m0, h);  float u0 = fmaxf(m0, h);
                    float n1 = fminf(m1, u0); float u1 = fmaxf(m1, u0);
                    float n2 = fminf(m2, u1); float u2 = fmaxf(m2, u1);
                    float n3 = fminf(m3, u2);
                    m0 = n0; m1 = n1; m2 = n2; m3 = n3;
                }
            }
        }
        l4[grp][threadIdx.x & 31] = make_float4(m0, m1, m2, m3);
        __syncthreads();
        if (threadIdx.x < 32) {
            float p0 = FLT_MAX, p1 = FLT_MAX, p2 = FLT_MAX, p3 = FLT_MAX;
            #pragma unroll
            for (int g2 = 0; g2 < 8; ++g2) {
                float4 v = l4[g2][threadIdx.x];
                const float vals[4] = {v.x, v.y, v.z, v.w};
                #pragma unroll
                for (int k = 0; k < 4; ++k) {
                    float h = vals[k];
                    if (h < p3) {
                        float n0 = fminf(p0, h);  float u0 = fmaxf(p0, h);
                        float n1 = fminf(p1, u0); float u1 = fmaxf(p1, u0);
                        float n2 = fminf(p2, u1); float u2 = fmaxf(p2, u1);
                        float n3 = fminf(p3, u2);
                        p0 = n0; p1 = n1; p2 = n2; p3 = n3;
                    }
                }
            }
            const float ms[4] = {p0, p1, p2, p3};
            #pragma unroll
            for (int k = 0; k < 4; ++k) {
                float d2 = fmaxf(ms[k], EPS_C);
                float d  = sqrtf(d2);
                contrib += (RADIUS_C - d) * expf(-d2 * (1.f / H2));
            }
        }
        if (threadIdx.x < 64) {                    // wave 0 only; lanes 32-63 hold 0
            #pragma unroll
            for (int off = 32; off > 0; off >>= 1)
                contrib += __shfl_down(contrib, off, 64);
            if (threadIdx.x == 0) repsum[c] = contrib;
        }
    }
}

// 1 block: sum 512 chamfer + 512 rep block-partials, write outputs.
__global__ __launch_bounds__(BLK) void finalize_kernel(
    const float* __restrict__ chamsum, const float* __restrict__ repsum,
    float* __restrict__ out)
{
    __shared__ float w[8];
    float s0 = chamsum[threadIdx.x] + chamsum[threadIdx.x + 256];
    float s1 = repsum[threadIdx.x]  + repsum[threadIdx.x + 256];
    #pragma unroll
    for (int off = 32; off > 0; off >>= 1) {
        s0 += __shfl_down(s0, off, 64);
        s1 += __shfl_down(s1, off, 64);
    }
    if ((threadIdx.x & 63) == 0) {
        w[(threadIdx.x >> 6) * 2 + 0] = s0;
        w[(threadIdx.x >> 6) * 2 + 1] = s1;
    }
    __syncthreads();
    if (threadIdx.x == 0) {
        float a0 = w[0] + w[2] + w[4] + w[6];
        float a1 = w[1] + w[3] + w[5] + w[7];
        out[0] = 100.f * a0 * (1.f / NQ);
        out[1] = a1 * (1.f / (NQ * 4));
    }
}

extern "C" void kernel_launch(void* const* d_in, const int* in_sizes, int n_in,
                              void* d_out, int out_size, void* d_ws, size_t ws_size,
                              hipStream_t stream)
{
    const float* pred = (const float*)d_in[0];
    const float* gt   = (const float*)d_in[1];

    float*  minseg  = (float*)d_ws;
    float4* top4    = (float4*)((char*)d_ws + (size_t)SEG_CH * NCH * sizeof(float));
    float*  chamsum = (float*)((char*)d_ws + (size_t)SEG_CH * NCH * sizeof(float)
                                           + (size_t)SEG_R * NQ * sizeof(float4));
    float*  repsum  = chamsum + 512;

    partial_kernel<<<1536, BLK, 0, stream>>>(pred, gt, minseg, top4);
    merge_kernel<<<1024, BLK, 0, stream>>>(minseg, top4, chamsum, repsum);
    finalize_kernel<<<1, BLK, 0, stream>>>(chamsum, repsum, (float*)d_out);
}

// Round 6
// 92.781 us; speedup vs baseline: 1.0890x; 1.0890x over previous
//
#include <hip/hip_runtime.h>
#include <float.h>
#include <math.h>

#define BATCH 4
#define NPTS 4096
#define BLK 256
#define QCH 8                      // queries/thread, chamfer
#define QR 4                       // queries/thread, repulsion
#define SEG_CH 64                  // chamfer segments (64 pts each)
#define TPTS_CH 64
#define SEG_R 64                   // repulsion segments (64 pts each)
#define TPTS_R 64
#define H2 (0.03f * 0.03f)
#define RADIUS_C 0.07f
#define EPS_C 1e-12f
#define T2 0.05f                   // rep d^2 cutoff: excluded contribs ~1e-25
#define NQ (BATCH * NPTS)          // 16384
#define NCH (2 * NQ)               // 32768 chamfer (type,b,q) rows
#define MBLK 1024                  // merge blocks (512 chamfer + 512 rep)

// d_ws (24 MB + 4 KB):  minseg @0 (8MB), top4 @8MB (16MB), sums @24MB.
//
// R13: revert R12 entirely (pk-fma regressed: v_pk_fma_f32 needs adjacent-VGPR
// pairs -> splat materialization per target ate the win). Base = R11 (92.95,
// best). New lever: partial is LDS(10.2us) + VALU(9.4us) running ~serially
// (~24us). Feed ODD targets via wave-uniform global reads (compiler -> s_load,
// scalar cache = 3rd pipe; |t|^2 recomputed per wave, same fma nesting =
// bit-identical), EVEN targets via LDS as before -> LDS wave-reads halve.
// Query setup hoisted above the barrier (independent of staging; barrier
// moved block-uniformly into each branch).

template <bool EXCL>
__device__ __forceinline__ void rep_loop(
    const float4* __restrict__ s, const float* __restrict__ tg, int base,
    const int (&q)[QR],
    const float (&nx)[QR], const float (&ny)[QR], const float (&nz)[QR],
    float (&m)[QR][4])
{
    #pragma unroll 2
    for (int j = 0; j < TPTS_R; j += 2) {
        float4 t0 = s[j];                                   // even: LDS broadcast
        float t1x = tg[3 * j + 3];                          // odd: uniform s_load
        float t1y = tg[3 * j + 4];
        float t1z = tg[3 * j + 5];
        float t1w = fmaf(t1x, t1x, fmaf(t1y, t1y, t1z * t1z));
        #pragma unroll
        for (int r = 0; r < QR; ++r) {
            float h0 = fmaf(nx[r], t0.x, fmaf(ny[r], t0.y, fmaf(nz[r], t0.z, t0.w)));
            if (EXCL) h0 = (base + j == q[r]) ? FLT_MAX : h0;
            if (__any(h0 < m[r][3])) {                      // per-query gate, rare
                float n0 = fminf(m[r][0], h0); float u0 = fmaxf(m[r][0], h0);
                float n1 = fminf(m[r][1], u0); float u1 = fmaxf(m[r][1], u0);
                float n2 = fminf(m[r][2], u1); float u2 = fmaxf(m[r][2], u1);
                float n3 = fminf(m[r][3], u2);
                m[r][0] = n0; m[r][1] = n1; m[r][2] = n2; m[r][3] = n3;
            }
        }
        #pragma unroll
        for (int r = 0; r < QR; ++r) {
            float h1 = fmaf(nx[r], t1x, fmaf(ny[r], t1y, fmaf(nz[r], t1z, t1w)));
            if (EXCL) h1 = (base + j + 1 == q[r]) ? FLT_MAX : h1;
            if (__any(h1 < m[r][3])) {
                float n0 = fminf(m[r][0], h1); float u0 = fmaxf(m[r][0], h1);
                float n1 = fminf(m[r][1], u0); float u1 = fmaxf(m[r][1], u0);
                float n2 = fminf(m[r][2], u1); float u2 = fmaxf(m[r][2], u1);
                float n3 = fminf(m[r][3], u2);
                m[r][0] = n0; m[r][1] = n1; m[r][2] = n2; m[r][3] = n3;
            }
        }
    }
}

// 2048 blocks: even bid = chamfer (qblk2 x type2 x b4 x seg64 = 1024),
//              odd  bid = repulsion (qblk4 x b4 x seg64 = 1024).
__global__ __launch_bounds__(BLK, 8) void partial_kernel(
    const float* __restrict__ pred, const float* __restrict__ gt,
    float* __restrict__ minseg, float4* __restrict__ top4)
{
    __shared__ float4 s[TPTS_R];   // 64 x (x,y,z,|t|^2) = 1 KB

    const int bid   = blockIdx.x;
    const int isrep = bid & 1;
    const int id    = bid >> 1;    // [0,1024)

    int type, b, qblk, seg;
    if (!isrep) {
        qblk = id & 1; type = (id >> 1) & 1; b = (id >> 2) & 3; seg = id >> 4;
    } else {
        qblk = id & 3; type = 2;             b = (id >> 2) & 3; seg = id >> 4;
    }
    const float* qbase = (type == 1) ? gt : pred;
    const float* tbase = (type == 0) ? gt : pred;
    const float* tg    = tbase + ((size_t)b * NPTS + seg * TPTS_R) * 3; // uniform

    // stage 64 targets: threads 0..31, 2 points each, |t|^2 on the fly
    if (threadIdx.x < 32) {
        const float2* g2 = (const float2*)tg;
        float2 a = g2[3 * threadIdx.x + 0];
        float2 c = g2[3 * threadIdx.x + 1];
        float2 e = g2[3 * threadIdx.x + 2];
        float t20 = fmaf(a.x, a.x, fmaf(a.y, a.y, c.x * c.x));
        float t21 = fmaf(c.y, c.y, fmaf(e.x, e.x, e.y * e.y));
        s[2 * threadIdx.x + 0] = make_float4(a.x, a.y, c.x, t20);
        s[2 * threadIdx.x + 1] = make_float4(c.y, e.x, e.y, t21);
    }

    if (!isrep) {
        const int q0 = qblk * (BLK * QCH) + threadIdx.x;      // qblk*2048 + tid
        float nx[QCH], ny[QCH], nz[QCH], q2[QCH], mn[QCH];
        #pragma unroll
        for (int k = 0; k < QCH; ++k) {                       // before barrier:
            const float* q = qbase + ((size_t)b * NPTS + q0 + k * BLK) * 3;
            float qx = q[0], qy = q[1], qz = q[2];            // hides under staging
            q2[k] = fmaf(qx, qx, fmaf(qy, qy, qz * qz));
            nx[k] = -2.f * qx; ny[k] = -2.f * qy; nz[k] = -2.f * qz;
            mn[k] = FLT_MAX;
        }
        __syncthreads();
        #pragma unroll 2
        for (int j = 0; j < TPTS_CH; j += 2) {
            float4 t0 = s[j];                                 // even: LDS
            float t1x = tg[3 * j + 3];                        // odd: uniform s_load
            float t1y = tg[3 * j + 4];
            float t1z = tg[3 * j + 5];
            float t1w = fmaf(t1x, t1x, fmaf(t1y, t1y, t1z * t1z));
            #pragma unroll
            for (int k = 0; k < QCH; ++k) {
                float h0 = fmaf(nx[k], t0.x, fmaf(ny[k], t0.y, fmaf(nz[k], t0.z, t0.w)));
                float h1 = fmaf(nx[k], t1x, fmaf(ny[k], t1y, fmaf(nz[k], t1z, t1w)));
                mn[k] = fminf(fminf(mn[k], h0), h1);          // -> v_min3_f32
            }
        }
        float* row = minseg + (size_t)seg * NCH + (type * BATCH + b) * NPTS;
        #pragma unroll
        for (int k = 0; k < QCH; ++k)
            row[q0 + k * BLK] = mn[k] + q2[k];
    } else {
        const int qb = qblk * (BLK * QR) + threadIdx.x;       // qblk*1024 + tid
        int   q[QR];
        float nx[QR], ny[QR], nz[QR], q2[QR];
        float m[QR][4];
        #pragma unroll
        for (int r = 0; r < QR; ++r) {                        // before barrier
            q[r] = qb + r * BLK;
            const float* qa = qbase + ((size_t)b * NPTS + q[r]) * 3;
            float qx = qa[0], qy = qa[1], qz = qa[2];
            q2[r] = fmaf(qx, qx, fmaf(qy, qy, qz * qz));
            nx[r] = -2.f * qx; ny[r] = -2.f * qy; nz[r] = -2.f * qz;
            // h-space cutoff init: h < T2 - q2  <=>  d2 < T2
            float a = T2 - q2[r];
            m[r][0] = a; m[r][1] = a; m[r][2] = a; m[r][3] = a;
        }
        __syncthreads();
        const int base = seg * TPTS_R;
        // queries [qblk*1024, +1024) overlap targets [seg*64, +64) iff seg>>4==qblk
        if ((seg >> 4) == qblk)
            rep_loop<true >(s, tg, base, q, nx, ny, nz, m);
        else
            rep_loop<false>(s, tg, base, q, nx, ny, nz, m);

        float4* dst = top4 + (size_t)seg * NQ + b * NPTS;
        #pragma unroll
        for (int r = 0; r < QR; ++r)
            dst[q[r]] = make_float4(m[r][0] + q2[r], m[r][1] + q2[r],
                                    m[r][2] + q2[r], m[r][3] + q2[r]);
    }
}

// 1024 blocks: even = chamfer merge (512 x 64 queries, 4 grp x 16 segs),
// odd = rep merge (512 x 32 queries, 8 grp x 8 segs). Seg-split across
// thread groups + LDS tree -> 1 latency round. NO atomics/fences: each
// block writes one float to chamsum[c]/repsum[c].
__global__ __launch_bounds__(BLK) void merge_kernel(
    const float* __restrict__ minseg, const float4* __restrict__ top4,
    float* __restrict__ chamsum, float* __restrict__ repsum)
{
    __shared__ float4 l4[8][32];                   // rep lists; aliased for chamfer
    float* red = (float*)l4;                       // [4][64] floats for chamfer

    float contrib = 0.f;
    const int c = blockIdx.x >> 1;                 // [0,512)
    if (!(blockIdx.x & 1)) {
        // ---- chamfer: 64 queries, 4 groups x 16 segs ----
        const int q   = c * 64 + (threadIdx.x & 63);
        const int grp = threadIdx.x >> 6;          // 0..3
        float m = FLT_MAX;
        #pragma unroll                             // 16 independent loads in flight
        for (int u = 0; u < 16; ++u)
            m = fminf(m, minseg[(size_t)(grp * 16 + u) * NCH + q]);
        red[grp * 64 + (threadIdx.x & 63)] = m;
        __syncthreads();
        if (threadIdx.x < 64) {
            float mm = fminf(fminf(red[threadIdx.x],       red[64  + threadIdx.x]),
                             fminf(red[128 + threadIdx.x], red[192 + threadIdx.x]));
            contrib = fmaxf(mm, 0.f);              // clamp as in reference
            #pragma unroll
            for (int off = 32; off > 0; off >>= 1)
                contrib += __shfl_down(contrib, off, 64);
            if (threadIdx.x == 0) chamsum[c] = contrib;
        }
    } else {
        // ---- repulsion: 32 queries, 8 groups x 8 segs ----
        const int q   = c * 32 + (threadIdx.x & 31);
        const int grp = threadIdx.x >> 5;          // 0..7
        float m0 = FLT_MAX, m1 = FLT_MAX, m2 = FLT_MAX, m3 = FLT_MAX;
        #pragma unroll                             // 8 float4 loads in flight
        for (int u = 0; u < 8; ++u) {
            float4 v = top4[(size_t)(grp * 8 + u) * NQ + q];
            const float vals[4] = {v.x, v.y, v.z, v.w};
            #pragma unroll
            for (int k = 0; k < 4; ++k) {
                float h = vals[k];
                if (h < m3) {                      // mostly T2 sentinel -> skip
                    float n0 = fminf(m0, h);  float u0 = fmaxf(m0, h);
                    float n1 = fminf(m1, u0); float u1 = fmaxf(m1, u0);
                    float n2 = fminf(m2, u1); float u2 = fmaxf(m2, u1);
                    float n3 = fminf(m3, u2);
                    m0 = n0; m1 = n1; m2 = n2; m3 = n3;
                }
            }
        }
        l4[grp][threadIdx.x & 31] = make_float4(m0, m1, m2, m3);
        __syncthreads();
        if (threadIdx.x < 32) {
            float p0 = FLT_MAX, p1 = FLT_MAX, p2 = FLT_MAX, p3 = FLT_MAX;
            #pragma unroll
            for (int g2 = 0; g2 < 8; ++g2) {
                float4 v = l4[g2][threadIdx.x];
                const float vals[4] = {v.x, v.y, v.z, v.w};
                #pragma unroll
                for (int k = 0; k < 4; ++k) {
                    float h = vals[k];
                    if (h < p3) {
                        float n0 = fminf(p0, h);  float u0 = fmaxf(p0, h);
                        float n1 = fminf(p1, u0); float u1 = fmaxf(p1, u0);
                        float n2 = fminf(p2, u1); float u2 = fmaxf(p2, u1);
                        float n3 = fminf(p3, u2);
                        p0 = n0; p1 = n1; p2 = n2; p3 = n3;
                    }
                }
            }
            const float ms[4] = {p0, p1, p2, p3};
            #pragma unroll
            for (int k = 0; k < 4; ++k) {
                float d2 = fmaxf(ms[k], EPS_C);
                float d  = sqrtf(d2);
                contrib += (RADIUS_C - d) * expf(-d2 * (1.f / H2));
            }
        }
        if (threadIdx.x < 64) {                    // wave 0 only; lanes 32-63 hold 0
            #pragma unroll
            for (int off = 32; off > 0; off >>= 1)
                contrib += __shfl_down(contrib, off, 64);
            if (threadIdx.x == 0) repsum[c] = contrib;
        }
    }
}

// 1 block: sum 512 chamfer + 512 rep block-partials, write outputs.
__global__ __launch_bounds__(BLK) void finalize_kernel(
    const float* __restrict__ chamsum, const float* __restrict__ repsum,
    float* __restrict__ out)
{
    __shared__ float w[8];
    float s0 = chamsum[threadIdx.x] + chamsum[threadIdx.x + 256];
    float s1 = repsum[threadIdx.x]  + repsum[threadIdx.x + 256];
    #pragma unroll
    for (int off = 32; off > 0; off >>= 1) {
        s0 += __shfl_down(s0, off, 64);
        s1 += __shfl_down(s1, off, 64);
    }
    if ((threadIdx.x & 63) == 0) {
        w[(threadIdx.x >> 6) * 2 + 0] = s0;
        w[(threadIdx.x >> 6) * 2 + 1] = s1;
    }
    __syncthreads();
    if (threadIdx.x == 0) {
        float a0 = w[0] + w[2] + w[4] + w[6];
        float a1 = w[1] + w[3] + w[5] + w[7];
        out[0] = 100.f * a0 * (1.f / NQ);
        out[1] = a1 * (1.f / (NQ * 4));
    }
}

extern "C" void kernel_launch(void* const* d_in, const int* in_sizes, int n_in,
                              void* d_out, int out_size, void* d_ws, size_t ws_size,
                              hipStream_t stream)
{
    const float* pred = (const float*)d_in[0];
    const float* gt   = (const float*)d_in[1];

    float*  minseg  = (float*)d_ws;
    float4* top4    = (float4*)((char*)d_ws + (size_t)SEG_CH * NCH * sizeof(float));
    float*  chamsum = (float*)((char*)d_ws + (size_t)SEG_CH * NCH * sizeof(float)
                                           + (size_t)SEG_R * NQ * sizeof(float4));
    float*  repsum  = chamsum + 512;

    partial_kernel<<<2048, BLK, 0, stream>>>(pred, gt, minseg, top4);
    merge_kernel<<<MBLK, BLK, 0, stream>>>(minseg, top4, chamsum, repsum);
    finalize_kernel<<<1, BLK, 0, stream>>>(chamsum, repsum, (float*)d_out);
}